// Round 1
// baseline (191.249 us; speedup 1.0000x reference)
//
#include <hip/hip_runtime.h>
#include <stdint.h>

typedef int v4i __attribute__((ext_vector_type(4)));

// Problem dims
#define N_IMG 32
#define C_IN 256
#define H_IN 56
#define W_IN 56
#define C_OUT 256
#define H_OUT 28
#define W_OUT 28
#define H_PAD 58
#define W_PAD 58
#define SP_TOT (N_IMG*H_OUT*W_OUT)   // 25088

#define XPAD_BYTES ((size_t)N_IMG*H_PAD*W_PAD*C_IN)   // 27,557,888 (16B aligned)

// Activations stored in NATURAL channel order.

__device__ __forceinline__ void glds16(const int8_t* g, int8_t* l) {
    __builtin_amdgcn_global_load_lds(
        (const __attribute__((address_space(1))) void*)g,
        (__attribute__((address_space(3))) void*)l, 16, 0, 0);
}

// ---------------------------------------------------------------------------
// Kernel 1 (v2): quantize fp32 NCHW -> int8 NHWC, borders inline.
// Grid (58, N), 256 thr. The old Phase-A LDS staging of raw fp32 was a pure
// pass-through (read back in the SAME (channel, w4-chunk) layout), so v2
// loads the float4 directly from global with the Phase-B pattern:
// lane (j,w4) reads channel 4*c4p+j, w = 4*w4..+3 (16B, aligned: row = 224B).
// Removes 57KB LDS write+read + one barrier; LDS 71.9KB -> 14.6KB so
// occupancy 2 -> >=4 blocks/CU. Quantize (x*20, rint, clamp), 2-step
// shfl_xor 4x4 byte transpose (verified R5), conflict-free ds_write_b32 to
// stride-65 u32 stage, then 256B/wave coalesced global writes.
// ---------------------------------------------------------------------------
__global__ __launch_bounds__(256, 4) void quant_kernel(const float* __restrict__ x,
                                                       int8_t* __restrict__ xpad) {
    __shared__ uint32_t ldsu[W_IN * 65];           // 14,560 B out-stage
    const int hp = blockIdx.x, n = blockIdx.y;
    const int t = threadIdx.x;
    int8_t* row = xpad + ((size_t)n * H_PAD + hp) * W_PAD * C_IN;

    if (hp == 0 || hp == H_PAD - 1) {
        // zero full padded row: 58*256 B = 928 x 16B
        #pragma unroll
        for (int i = 0; i < 4; ++i) {
            int idx = i * 256 + t;
            if (idx < 928) *(int4*)(row + idx * 16) = (int4){0, 0, 0, 0};
        }
        return;
    }
    const int h = hp - 1;
    const float* xrow = x + (size_t)n * (C_IN * H_IN * W_IN) + (size_t)h * W_IN;

    // zero border pixels w_p = 0 and w_p = 57 (32 x 16B), independent of loads
    if (t < 32) {
        int8_t* p = (t < 16) ? (row + t * 16)
                             : (row + (size_t)(W_PAD - 1) * C_IN + (t - 16) * 16);
        *(int4*)p = (int4){0, 0, 0, 0};
    }

    // ---- quantize + 4x4 shfl byte transpose -> ldsu (direct global reads) ----
    const int lane = t & 63, wv = t >> 6;
    const int j = lane >> 4, w4 = lane & 15;
    const int w4c = (w4 < 14) ? w4 : 13;           // clamp reads; store masked
    #pragma unroll
    for (int i16 = 0; i16 < 16; ++i16) {
        const int c4p = i16 * 4 + wv;              // output word index 0..63
        const float4 v = *(const float4*)(xrow + (size_t)(4 * c4p + j) * (H_IN * W_IN)
                                          + w4c * 4);
        float f[4] = {v.x, v.y, v.z, v.w};
        uint32_t u = 0;
        #pragma unroll
        for (int i = 0; i < 4; ++i) {
            float qv = rintf(f[i] * 20.0f);        // ~= x/0.05, see R4 notes
            qv = fminf(fmaxf(qv, -128.0f), 127.0f);
            u |= ((uint32_t)((int)qv & 255)) << (8 * i);  // byte i = w-offset i
        }
        // 4x4 byte transpose across lanes {j, same w4}  [verified R5]
        uint32_t p1 = __shfl_xor(u, 16);
        uint32_t tt = (j & 1) ? (((p1 >> 8) & 0x00FF00FFu) | (u & 0xFF00FF00u))
                              : ((u & 0x00FF00FFu) | ((p1 << 8) & 0xFF00FF00u));
        uint32_t p2 = __shfl_xor(tt, 32);
        uint32_t rr = (j & 2) ? ((p2 >> 16) | (tt & 0xFFFF0000u))
                              : ((tt & 0x0000FFFFu) | (p2 << 16));
        // lane now holds w = 4*w4 + j, channels 4*c4p .. 4*c4p+3 (natural order)
        if (w4 < 14) ldsu[(w4 * 4 + j) * 65 + c4p] = rr;
    }
    __syncthreads();

    // ---- write x_pad[n][hp][w+1][c], 256B/wave coalesced ----
    int8_t* op = row + C_IN;                       // w_p starts at 1
    #pragma unroll
    for (int it = 0; it < 14; ++it) {              // 56 w * 64 c4 = 3584
        int idx = it * 256 + t;
        int w = idx >> 6, c4 = idx & 63;
        *(uint32_t*)(op + (size_t)w * C_IN + c4 * 4) = ldsu[w * 65 + c4];
    }
}

// ---------------------------------------------------------------------------
// Kernel 2: repack weights fp32 [co][ci][kh][kw] -> int8 wq[khw][co][ci]
// ---------------------------------------------------------------------------
__global__ __launch_bounds__(256) void wq_kernel(const float* __restrict__ w,
                                                 int8_t* __restrict__ wq) {
    int idx = blockIdx.x * 256 + threadIdx.x;   // < 9*256*256 = 589824
    int ci  = idx & 255;
    int co  = (idx >> 8) & 255;
    int khw = idx >> 16;
    float v = w[(size_t)(co * C_IN + ci) * 9 + khw];
    wq[idx] = (int8_t)(int)rintf(v);
}

// ---------------------------------------------------------------------------
// Kernel 3 (v2): implicit-GEMM conv, double-buffered LDS (T3 2-phase).
// Tile 64co x 64sp, 256 thr = 4 waves of 32co x 32sp -> grid 392 x 4.
// 18 half-tap stages (BK=128: 8KB W + 8KB Act per stage) so 2 buffers fit
// in 32KB LDS -> keeps 5 blocks/CU (m132 lesson: occupancy > fat K-tiles).
// Loop: stage(s+1 -> other buf) BEFORE compute(s); ONE __syncthreads per
// stage (its vmcnt(0) drain completes DMA(s+1) and frees buf for overwrite)
// -> DMA stays in flight across the MFMA cluster instead of the old
// issue->drain->compute serialization (2 barriers/stage).
// Swizzle re-derived for 128B rows: LDS[row][y] = global[row][y^(row&7)],
// read chunk st = ((ks*4+q)^(s&7))*16; s/s+8 alias is 2-way = free (m136).
// C/D: col(sp) = s, row(co) = q*4 + reg   [verified mapping]
// ---------------------------------------------------------------------------
__global__ __launch_bounds__(256) void conv_kernel(const int8_t* __restrict__ xpad,
                                                   const int8_t* __restrict__ wq,
                                                   float* __restrict__ out) {
    __shared__ __align__(16) int8_t lds[32768];  // buf b at b*16384: [W 8K][Act 8K]
    const int t = threadIdx.x;
    const int wave = t >> 6, lane = t & 63;
    const int q = lane >> 4, s = lane & 15;
    const int co_blk = blockIdx.y * 64;
    const int sp_blk = blockIdx.x * 64;

    // ---- staging decode: thread t covers rows r0 and r0+32, chunk x = t&7 ----
    const int r0 = t >> 3;                        // 0..31
    const int xch = ((t & 7) ^ (r0 & 7)) * 16;    // pre-swizzled source chunk
    const int8_t* gw2[2];
    const int8_t* ga2[2];
    #pragma unroll
    for (int jj = 0; jj < 2; ++jj) {
        const int r = r0 + jj * 32;
        gw2[jj] = wq + (size_t)(co_blk + r) * 256 + xch;
        int sp = sp_blk + r;
        int n  = sp / (H_OUT * W_OUT);
        int rm = sp - n * (H_OUT * W_OUT);
        int ho = rm / W_OUT;
        int wo = rm - ho * W_OUT;
        ga2[jj] = xpad + ((size_t)(n * H_PAD + ho * 2) * W_PAD + wo * 2) * C_IN + xch;
    }

    // ---- output mapping ----
    const int cw = (wave >> 1) * 32;          // LDS-local co base of this wave
    const int sw = (wave & 1) * 32;           // LDS-local sp base of this wave
    int out_base[2];
    #pragma unroll
    for (int jj = 0; jj < 2; ++jj) {
        int sp = sp_blk + sw + jj * 16 + s;
        int n  = sp / (H_OUT * W_OUT);
        int rm = sp - n * (H_OUT * W_OUT);
        int ho = rm / W_OUT;
        int wo = rm - ho * W_OUT;
        out_base[jj] = n * (C_OUT * H_OUT * W_OUT) + ho * W_OUT + wo;
    }

    v4i acc[2][2];
    #pragma unroll
    for (int i = 0; i < 2; ++i)
        #pragma unroll
        for (int jj = 0; jj < 2; ++jj)
            acc[i][jj] = (v4i){0, 0, 0, 0};

    // stage half-tap hk (tap = hk>>1, half = hk&1) into buffer bufb
    auto stage = [&](int hk, int bufb) {
        const int tap = hk >> 1, hf = hk & 1;
        const int wo_ = tap * (C_OUT * C_IN) + hf * 128;
        const int ao_ = ((tap / 3) * W_PAD + (tap % 3)) * C_IN + hf * 128;
        int8_t* lb = lds + bufb * 16384;
        #pragma unroll
        for (int jj = 0; jj < 2; ++jj) {
            glds16(gw2[jj] + wo_, lb + (t + jj * 256) * 16);            // W 8KB
            glds16(ga2[jj] + ao_, lb + 8192 + (t + jj * 256) * 16);     // Act 8KB
        }
    };

    // compute one half-tap from buffer bufb (K = 128 -> 2 MFMA k-slices)
    auto compute = [&](int bufb) {
        const int8_t* lb = lds + bufb * 16384;
        #pragma unroll
        for (int ks = 0; ks < 2; ++ks) {
            const int st = ((ks * 4 + q) ^ (s & 7)) * 16;  // swizzled chunk
            v4i a[2], b[2];
            #pragma unroll
            for (int i = 0; i < 2; ++i)
                a[i] = *(const v4i*)(lb + (cw + i * 16 + s) * 128 + st);
            #pragma unroll
            for (int jj = 0; jj < 2; ++jj)
                b[jj] = *(const v4i*)(lb + 8192 + (sw + jj * 16 + s) * 128 + st);
            #pragma unroll
            for (int i = 0; i < 2; ++i)
                #pragma unroll
                for (int jj = 0; jj < 2; ++jj)
                    acc[i][jj] = __builtin_amdgcn_mfma_i32_16x16x64_i8(
                        a[i], b[jj], acc[i][jj], 0, 0, 0);
        }
    };

    // ---- K loop: prologue + 18 double-buffered half-tap stages ----
    stage(0, 0);
    __syncthreads();                           // vmcnt(0) drain: buf0 ready
    #pragma unroll
    for (int hk = 0; hk < 18; ++hk) {
        const int cb = hk & 1;
        if (hk < 17) stage(hk + 1, cb ^ 1);    // DMA next stage, stays in flight
        compute(cb);                           // MFMA cluster overlaps the DMA
        if (hk < 17) __syncthreads();          // drains DMA(hk+1); frees buf cb
    }

    // ---- epilogue: coalesced dword stores (lanes 0-15 = consecutive sp) ----
    #pragma unroll
    for (int jj = 0; jj < 2; ++jj) {
        #pragma unroll
        for (int i = 0; i < 2; ++i) {
            const int co0 = co_blk + cw + i * 16 + q * 4;
            #pragma unroll
            for (int r = 0; r < 4; ++r) {
                out[(size_t)out_base[jj] + (size_t)(co0 + r) * (H_OUT * W_OUT)] =
                    (float)acc[i][jj][r] * 0.0005f;
            }
        }
    }
}

// ---------------------------------------------------------------------------
extern "C" void kernel_launch(void* const* d_in, const int* in_sizes, int n_in,
                              void* d_out, int out_size, void* d_ws, size_t ws_size,
                              hipStream_t stream) {
    const float* x = (const float*)d_in[0];
    const float* w = (const float*)d_in[1];
    float* out = (float*)d_out;
    int8_t* xpad = (int8_t*)d_ws;
    int8_t* wqb  = xpad + XPAD_BYTES;

    quant_kernel<<<dim3(H_PAD, N_IMG), 256, 0, stream>>>(x, xpad);
    wq_kernel<<<(9 * C_OUT * C_IN) / 256, 256, 0, stream>>>(w, wqb);
    conv_kernel<<<dim3(SP_TOT / 64, C_OUT / 64), 256, 0, stream>>>(xpad, wqb, out);
}